// Round 4
// baseline (160.245 us; speedup 1.0000x reference)
//
#include <hip/hip_runtime.h>
#include <hip/hip_bf16.h>
#include <cstdint>
#include <cstddef>

#define TOK 8192
#define HID 1024
#define NE 8

typedef __bf16 bf16x4 __attribute__((ext_vector_type(4)));
typedef __bf16 bf16x8 __attribute__((ext_vector_type(8)));
typedef float floatx4 __attribute__((ext_vector_type(4)));

static __device__ __forceinline__ __bf16 f2bf(float x) {
    unsigned u = __builtin_bit_cast(unsigned, x);
    u += 0x7fffu + ((u >> 16) & 1u);   // RNE (inputs finite)
    unsigned short hs = (unsigned short)(u >> 16);
    return __builtin_bit_cast(__bf16, hs);
}

// Fused prep:
//   blocks [0, 4096):    X fp32 -> Xb bf16 (8 elems/thread); blocks [0,32) also route.
//   blocks [4096, 4608): W [E][K][N] fp32 -> Wt [E][N][K] bf16 via register 8x8
//                        micro-transpose (no LDS): reads 256B runs, writes full
//                        128B lines per wave.
__global__ void prep_kernel(const float* __restrict__ X, const float* __restrict__ gate,
                            const float* __restrict__ W,
                            __bf16* __restrict__ Xb, __bf16* __restrict__ Wt,
                            float* __restrict__ scale, int* __restrict__ counts,
                            int* __restrict__ list) {
    const int b = blockIdx.x;
    const int t = threadIdx.x;

    if (b < 4096) {
        // ---- cvt_x ----
        size_t idx = (size_t)b * 256 + t;
        const float4 a0 = *(const float4*)(X + idx * 8);
        const float4 a1 = *(const float4*)(X + idx * 8 + 4);
        bf16x8 v;
        v[0] = f2bf(a0.x); v[1] = f2bf(a0.y); v[2] = f2bf(a0.z); v[3] = f2bf(a0.w);
        v[4] = f2bf(a1.x); v[5] = f2bf(a1.y); v[6] = f2bf(a1.z); v[7] = f2bf(a1.w);
        *(bf16x8*)(Xb + idx * 8) = v;

        // ---- route (blocks 0..31, one token per thread, LDS histogram) ----
        if (b < 32) {
            __shared__ int hcnt[NE];
            __shared__ int hbase[NE];
            if (t < NE) hcnt[t] = 0;
            __syncthreads();
            int tok = b * 256 + t;
            float g[NE];
#pragma unroll
            for (int j = 0; j < NE; j++) g[j] = gate[tok * NE + j];
            float gm = g[0]; int best = 0;
#pragma unroll
            for (int j = 1; j < NE; j++) {
                if (g[j] > gm) { gm = g[j]; best = j; }   // strict >: first-max (argmax)
            }
            float s = 0.f;
#pragma unroll
            for (int j = 0; j < NE; j++) s += __expf(g[j] - gm);
            scale[tok] = 1.0f / s;
            int lpos = atomicAdd(&hcnt[best], 1);
            __syncthreads();
            if (t < NE) hbase[t] = atomicAdd(&counts[t], hcnt[t]);
            __syncthreads();
            list[best * TOK + hbase[best] + lpos] = tok;
        }
    } else {
        // ---- cvt_wt: register micro-transpose. Block tile: k in [0,256), n in [0,64). ----
        const int bb = b - 4096;            // 0..511
        const int e  = bb >> 6;
        const int kt = (bb >> 4) & 3;
        const int nt = bb & 15;
        const int k0 = kt * 256, n0 = nt * 64;
        const int ka = t >> 3;              // 0..31: k-micro (8 rows)
        const int nb = t & 7;               // 0..7:  n-micro (8 cols)

        const float* src = W + ((size_t)e * HID + k0 + ka * 8) * HID + n0 + nb * 8;
        float rr[8][8];
#pragma unroll
        for (int i = 0; i < 8; i++) {
            float4 x = *(const float4*)(src + (size_t)i * HID);
            float4 y = *(const float4*)(src + (size_t)i * HID + 4);
            rr[i][0] = x.x; rr[i][1] = x.y; rr[i][2] = x.z; rr[i][3] = x.w;
            rr[i][4] = y.x; rr[i][5] = y.y; rr[i][6] = y.z; rr[i][7] = y.w;
        }
        __bf16* dst = Wt + ((size_t)e * HID + n0 + nb * 8) * HID + k0 + ka * 8;
#pragma unroll
        for (int j = 0; j < 8; j++) {
            bf16x8 v;
#pragma unroll
            for (int i = 0; i < 8; i++) v[i] = f2bf(rr[i][j]);
            *(bf16x8*)(dst + (size_t)j * HID) = v;
        }
    }
}

// Grouped GEMM. Swizzles:
//  * Expert-per-XCD: bid = (mt*8 + nt)*8 + e -> XCD (bid%8) == e. Per XCD the working
//    set is this expert's A rows (~2MB bf16) + its Wt (2MB bf16): both L2-resident.
//  * LDS chunk swizzle: element-chunk c of row r lives at slot c^(r&7) (row stride 64
//    bf16 = 32 banks); staging fetches global chunk (p^srow) so the wave-uniform
//    global_load_lds dest (base + lane*16) lands each chunk in its swizzled slot.
//  * Double-buffered LDS: loads for k+1 issued right after the barrier, overlapping
//    compute on k (only ~2 blocks/CU here, so implicit wave overlap is weak).
//  * Nontemporal epilogue stores keep the output stream from evicting A/B in L2.
__launch_bounds__(256)
__global__ void moe_gemm_bf16(const __bf16* __restrict__ Xb, const __bf16* __restrict__ Wt,
                              const float* __restrict__ Bias, const float* __restrict__ scale,
                              const int* __restrict__ counts, const int* __restrict__ list,
                              float* __restrict__ out) {
    const int bid = blockIdx.x;
    const int e  = bid & 7;
    const int nt = (bid >> 3) & 7;
    const int mt = bid >> 6;

    const int cnt = counts[e];
    if (mt * 128 >= cnt) return;
    const int mvalid = min(128, cnt - mt * 128);
    const int n0 = nt * 128;

    __shared__ __bf16 As[2][128 * 64];
    __shared__ __bf16 Bs[2][128 * 64];
    __shared__ int   tok[128];
    __shared__ float scl[128];

    const int tid  = threadIdx.x;
    const int lane = tid & 63;
    const int wave = tid >> 6;

    if (tid < 128) {
        int g = mt * 128 + tid;
        int tk = (g < cnt) ? list[e * TOK + g] : 0;
        tok[tid] = tk;
        scl[tid] = (g < cnt) ? scale[tk] : 0.f;
    }
    __syncthreads();

    // Staging: wave w, step i covers LDS rows w*32+i*8..+8 (1KB contiguous).
    const int srow = lane >> 3;
    const int gchunk = ((lane & 7) ^ srow) * 8;
    const __bf16* aptr[4];
    const __bf16* bptr[4];
#pragma unroll
    for (int i = 0; i < 4; i++) {
        int r = wave * 32 + i * 8 + srow;
        aptr[i] = Xb + (size_t)tok[r] * HID + gchunk;
        bptr[i] = Wt + ((size_t)e * HID + n0 + r) * HID + gchunk;
    }

    const int ln = lane & 15;
    const int q  = lane >> 4;
    const int wm = (wave >> 1) * 64;
    const int wn = (wave & 1) * 64;
    const int rsw = ln & 7;

    floatx4 acc[4][4];
#pragma unroll
    for (int mi = 0; mi < 4; mi++)
#pragma unroll
        for (int ni = 0; ni < 4; ni++) acc[mi][ni] = (floatx4){0.f, 0.f, 0.f, 0.f};

    auto stage = [&](int kt, int buf) {
        const int k0 = kt * 64;
#pragma unroll
        for (int i = 0; i < 4; i++) {
            __builtin_amdgcn_global_load_lds(
                (const __attribute__((address_space(1))) void*)(aptr[i] + k0),
                (__attribute__((address_space(3))) void*)(&As[buf][(wave * 32 + i * 8) * 64]),
                16, 0, 0);
            __builtin_amdgcn_global_load_lds(
                (const __attribute__((address_space(1))) void*)(bptr[i] + k0),
                (__attribute__((address_space(3))) void*)(&Bs[buf][(wave * 32 + i * 8) * 64]),
                16, 0, 0);
        }
    };

    stage(0, 0);
    for (int kt = 0; kt < 16; ++kt) {
        __syncthreads();                     // drains vmcnt: buf[kt&1] is ready
        if (kt < 15) stage(kt + 1, (kt + 1) & 1);
        const int buf = kt & 1;

#pragma unroll
        for (int kk = 0; kk < 64; kk += 32) {
            const int cb = (kk >> 3) + q;
            const int pos = (cb ^ rsw) * 8;
            bf16x8 af[4], bfv[4];
#pragma unroll
            for (int mi = 0; mi < 4; mi++)
                af[mi] = *(const bf16x8*)(&As[buf][(wm + mi * 16 + ln) * 64 + pos]);
#pragma unroll
            for (int ni = 0; ni < 4; ni++)
                bfv[ni] = *(const bf16x8*)(&Bs[buf][(wn + ni * 16 + ln) * 64 + pos]);
#pragma unroll
            for (int mi = 0; mi < 4; mi++)
#pragma unroll
                for (int ni = 0; ni < 4; ni++)
                    acc[mi][ni] = __builtin_amdgcn_mfma_f32_16x16x32_bf16(
                        af[mi], bfv[ni], acc[mi][ni], 0, 0, 0);
        }
    }

    float bn[4];
#pragma unroll
    for (int ni = 0; ni < 4; ni++) bn[ni] = Bias[e * HID + n0 + wn + ni * 16 + ln];

#pragma unroll
    for (int mi = 0; mi < 4; mi++) {
#pragma unroll
        for (int r = 0; r < 4; r++) {
            int row = wm + mi * 16 + q * 4 + r;
            if (row < mvalid) {
                int t = tok[row];
                float sc = scl[row];
                size_t ob = (size_t)t * HID + n0 + wn + ln;
#pragma unroll
                for (int ni = 0; ni < 4; ni++)
                    __builtin_nontemporal_store(sc * (acc[mi][ni][r] + bn[ni]),
                                                &out[ob + ni * 16]);
            }
        }
    }
}

// ---------------- fallback (ws too small): direct fp32 reads, compile-time j ----------------
__launch_bounds__(256)
__global__ void moe_gemm_fb(const float* __restrict__ X, const float* __restrict__ W,
                            const float* __restrict__ Bias, const float* __restrict__ scale,
                            const int* __restrict__ counts, const int* __restrict__ list,
                            float* __restrict__ out) {
    const int bid = blockIdx.x;
    const int e  = bid >> 9;
    const int nt = (bid >> 6) & 7;
    const int mt = bid & 63;
    const int cnt = counts[e];
    if (mt * 128 >= cnt) return;
    const int mvalid = min(128, cnt - mt * 128);
    const int n0 = nt * 128;

    __shared__ __bf16 As[128 * 64];
    __shared__ __bf16 Bs[128 * 64];
    __shared__ int   tok[128];
    __shared__ float scl[128];

    const int tid = threadIdx.x;
    if (tid < 128) {
        int g = mt * 128 + tid;
        int tk = (g < cnt) ? list[e * TOK + g] : 0;
        tok[tid] = tk;
        scl[tid] = (g < cnt) ? scale[tk] : 0.f;
    }
    __syncthreads();

    const int c4 = tid & 15;
    const float* rp[8];
    bool rv[8];
#pragma unroll
    for (int i = 0; i < 8; i++) {
        int m = (tid >> 4) + 16 * i;
        rv[i] = (m < mvalid);
        rp[i] = X + (size_t)tok[m] * HID;
    }
    const int n4 = tid & 31;
    const int kb = tid >> 5;
    const float* wbase = W + (size_t)e * HID * HID + (size_t)(kb * 8) * HID + n0 + n4 * 4;

    const int lane = tid & 63;
    const int ln = lane & 15;
    const int q  = lane >> 4;
    const int wave = tid >> 6;
    const int wm = (wave >> 1) * 64;
    const int wn = (wave & 1) * 64;

    floatx4 acc[4][4];
#pragma unroll
    for (int mi = 0; mi < 4; mi++)
#pragma unroll
        for (int ni = 0; ni < 4; ni++) acc[mi][ni] = (floatx4){0.f, 0.f, 0.f, 0.f};

    for (int k0 = 0; k0 < HID; k0 += 64) {
#pragma unroll
        for (int i = 0; i < 8; i++) {
            int m = (tid >> 4) + 16 * i;
            float4 v = make_float4(0.f, 0.f, 0.f, 0.f);
            if (rv[i]) v = *(const float4*)(rp[i] + k0 + c4 * 4);
            bf16x4 b4;
            b4[0] = f2bf(v.x); b4[1] = f2bf(v.y); b4[2] = f2bf(v.z); b4[3] = f2bf(v.w);
            int chunk = c4 >> 1;
            int addr = m * 64 + ((chunk ^ (m & 7)) * 8) + (c4 & 1) * 4;
            *(bf16x4*)(&As[addr]) = b4;
        }
        {
            const float* wp = wbase + (size_t)k0 * HID;
            float4 rr[8];
#pragma unroll
            for (int r = 0; r < 8; r++) rr[r] = *(const float4*)(wp + (size_t)r * HID);
#pragma unroll
            for (int j = 0; j < 4; j++) {
                int n = n4 * 4 + j;
                int c = kb ^ (n & 7);
                bf16x8 pk;
                pk[0] = f2bf(j == 0 ? rr[0].x : j == 1 ? rr[0].y : j == 2 ? rr[0].z : rr[0].w);
                pk[1] = f2bf(j == 0 ? rr[1].x : j == 1 ? rr[1].y : j == 2 ? rr[1].z : rr[1].w);
                pk[2] = f2bf(j == 0 ? rr[2].x : j == 1 ? rr[2].y : j == 2 ? rr[2].z : rr[2].w);
                pk[3] = f2bf(j == 0 ? rr[3].x : j == 1 ? rr[3].y : j == 2 ? rr[3].z : rr[3].w);
                pk[4] = f2bf(j == 0 ? rr[4].x : j == 1 ? rr[4].y : j == 2 ? rr[4].z : rr[4].w);
                pk[5] = f2bf(j == 0 ? rr[5].x : j == 1 ? rr[5].y : j == 2 ? rr[5].z : rr[5].w);
                pk[6] = f2bf(j == 0 ? rr[6].x : j == 1 ? rr[6].y : j == 2 ? rr[6].z : rr[6].w);
                pk[7] = f2bf(j == 0 ? rr[7].x : j == 1 ? rr[7].y : j == 2 ? rr[7].z : rr[7].w);
                *(bf16x8*)(&Bs[n * 64 + c * 8]) = pk;
            }
        }
        __syncthreads();
#pragma unroll
        for (int kk = 0; kk < 64; kk += 32) {
            const int cbase = (kk >> 3) + q;
            bf16x8 af[4], bfv[4];
#pragma unroll
            for (int mi = 0; mi < 4; mi++) {
                int row = wm + mi * 16 + ln;
                af[mi] = *(const bf16x8*)(&As[row * 64 + ((cbase ^ (row & 7)) * 8)]);
            }
#pragma unroll
            for (int ni = 0; ni < 4; ni++) {
                int n = wn + ni * 16 + ln;
                bfv[ni] = *(const bf16x8*)(&Bs[n * 64 + ((cbase ^ (n & 7)) * 8)]);
            }
#pragma unroll
            for (int mi = 0; mi < 4; mi++)
#pragma unroll
                for (int ni = 0; ni < 4; ni++)
                    acc[mi][ni] = __builtin_amdgcn_mfma_f32_16x16x32_bf16(
                        af[mi], bfv[ni], acc[mi][ni], 0, 0, 0);
        }
        __syncthreads();
    }

    float bn[4];
#pragma unroll
    for (int ni = 0; ni < 4; ni++) bn[ni] = Bias[e * HID + n0 + wn + ni * 16 + ln];
#pragma unroll
    for (int mi = 0; mi < 4; mi++) {
#pragma unroll
        for (int r = 0; r < 4; r++) {
            int row = wm + mi * 16 + q * 4 + r;
            if (row < mvalid) {
                int t = tok[row];
                float sc = scl[row];
                size_t ob = (size_t)t * HID + n0 + wn + ln;
#pragma unroll
                for (int ni = 0; ni < 4; ni++)
                    out[ob + ni * 16] = sc * (acc[mi][ni][r] + bn[ni]);
            }
        }
    }
}

__global__ void route_fb_kernel(const float* __restrict__ gate, float* __restrict__ scale,
                                int* __restrict__ counts, int* __restrict__ list) {
    int t = blockIdx.x * blockDim.x + threadIdx.x;
    if (t >= TOK) return;
    float g[NE];
#pragma unroll
    for (int j = 0; j < NE; j++) g[j] = gate[t * NE + j];
    float gm = g[0]; int best = 0;
#pragma unroll
    for (int j = 1; j < NE; j++) {
        if (g[j] > gm) { gm = g[j]; best = j; }
    }
    float s = 0.f;
#pragma unroll
    for (int j = 0; j < NE; j++) s += __expf(g[j] - gm);
    scale[t] = 1.0f / s;
    int pos = atomicAdd(&counts[best], 1);
    list[best * TOK + pos] = t;
}

extern "C" void kernel_launch(void* const* d_in, const int* in_sizes, int n_in,
                              void* d_out, int out_size, void* d_ws, size_t ws_size,
                              hipStream_t stream) {
    const float* X    = (const float*)d_in[0];
    const float* G    = (const float*)d_in[1];
    const float* W    = (const float*)d_in[2];
    const float* Bias = (const float*)d_in[3];
    float* out = (float*)d_out;

    float* scale = (float*)d_ws;                               // 32 KB
    int* counts  = (int*)((char*)d_ws + 32768);                // 32 B (+pad)
    int* list    = (int*)((char*)d_ws + 36864);                // 256 KB -> ends 299008
    __bf16* Xb   = (__bf16*)((char*)d_ws + 299008);            // 16 MB
    __bf16* Wt   = (__bf16*)((char*)d_ws + 299008 + 16777216); // 16 MB
    const size_t need = 299008 + 2 * 16777216ULL;

    hipMemsetAsync(counts, 0, NE * sizeof(int), stream);

    if (ws_size >= need) {
        prep_kernel<<<4608, 256, 0, stream>>>(X, G, W, Xb, Wt, scale, counts, list);
        moe_gemm_bf16<<<NE * 64 * 8, 256, 0, stream>>>(Xb, Wt, Bias, scale, counts, list, out);
    } else {
        route_fb_kernel<<<TOK / 256, 256, 0, stream>>>(G, scale, counts, list);
        moe_gemm_fb<<<NE * 64 * 8, 256, 0, stream>>>(X, W, Bias, scale, counts, list, out);
    }
}

// Round 5
// 149.757 us; speedup vs baseline: 1.0700x; 1.0700x over previous
//
#include <hip/hip_runtime.h>
#include <hip/hip_bf16.h>
#include <cstdint>
#include <cstddef>

#define TOK 8192
#define HID 1024
#define NE 8

typedef __bf16 bf16x4 __attribute__((ext_vector_type(4)));
typedef __bf16 bf16x8 __attribute__((ext_vector_type(8)));
typedef float floatx4 __attribute__((ext_vector_type(4)));

static __device__ __forceinline__ __bf16 f2bf(float x) {
    unsigned u = __builtin_bit_cast(unsigned, x);
    u += 0x7fffu + ((u >> 16) & 1u);   // RNE (inputs finite)
    unsigned short hs = (unsigned short)(u >> 16);
    return __builtin_bit_cast(__bf16, hs);
}

// Fused prep:
//   blocks [0, 4096):    X fp32 -> Xb bf16 (8 elems/thread); blocks [0,32) also route.
//   blocks [4096, 4608): W [E][K][N] fp32 -> Wt [E][N][K] bf16 via register 8x8
//                        micro-transpose (no LDS).
__global__ void prep_kernel(const float* __restrict__ X, const float* __restrict__ gate,
                            const float* __restrict__ W,
                            __bf16* __restrict__ Xb, __bf16* __restrict__ Wt,
                            float* __restrict__ scale, int* __restrict__ counts,
                            int* __restrict__ list) {
    const int b = blockIdx.x;
    const int t = threadIdx.x;

    if (b < 4096) {
        // ---- cvt_x ----
        size_t idx = (size_t)b * 256 + t;
        const float4 a0 = *(const float4*)(X + idx * 8);
        const float4 a1 = *(const float4*)(X + idx * 8 + 4);
        bf16x8 v;
        v[0] = f2bf(a0.x); v[1] = f2bf(a0.y); v[2] = f2bf(a0.z); v[3] = f2bf(a0.w);
        v[4] = f2bf(a1.x); v[5] = f2bf(a1.y); v[6] = f2bf(a1.z); v[7] = f2bf(a1.w);
        *(bf16x8*)(Xb + idx * 8) = v;

        // ---- route (blocks 0..31, one token per thread, LDS histogram) ----
        if (b < 32) {
            __shared__ int hcnt[NE];
            __shared__ int hbase[NE];
            if (t < NE) hcnt[t] = 0;
            __syncthreads();
            int tok = b * 256 + t;
            float g[NE];
#pragma unroll
            for (int j = 0; j < NE; j++) g[j] = gate[tok * NE + j];
            float gm = g[0]; int best = 0;
#pragma unroll
            for (int j = 1; j < NE; j++) {
                if (g[j] > gm) { gm = g[j]; best = j; }   // strict >: first-max (argmax)
            }
            float s = 0.f;
#pragma unroll
            for (int j = 0; j < NE; j++) s += __expf(g[j] - gm);
            scale[tok] = 1.0f / s;
            int lpos = atomicAdd(&hcnt[best], 1);
            __syncthreads();
            if (t < NE) hbase[t] = atomicAdd(&counts[t], hcnt[t]);
            __syncthreads();
            list[best * TOK + hbase[best] + lpos] = tok;
        }
    } else {
        // ---- cvt_wt: register micro-transpose. Block tile: k in [0,256), n in [0,64). ----
        const int bb = b - 4096;            // 0..511
        const int e  = bb >> 6;
        const int kt = (bb >> 4) & 3;
        const int nt = bb & 15;
        const int k0 = kt * 256, n0 = nt * 64;
        const int ka = t >> 3;              // 0..31: k-micro (8 rows)
        const int nb = t & 7;               // 0..7:  n-micro (8 cols)

        const float* src = W + ((size_t)e * HID + k0 + ka * 8) * HID + n0 + nb * 8;
        float rr[8][8];
#pragma unroll
        for (int i = 0; i < 8; i++) {
            float4 x = *(const float4*)(src + (size_t)i * HID);
            float4 y = *(const float4*)(src + (size_t)i * HID + 4);
            rr[i][0] = x.x; rr[i][1] = x.y; rr[i][2] = x.z; rr[i][3] = x.w;
            rr[i][4] = y.x; rr[i][5] = y.y; rr[i][6] = y.z; rr[i][7] = y.w;
        }
        __bf16* dst = Wt + ((size_t)e * HID + n0 + nb * 8) * HID + k0 + ka * 8;
#pragma unroll
        for (int j = 0; j < 8; j++) {
            bf16x8 v;
#pragma unroll
            for (int i = 0; i < 8; i++) v[i] = f2bf(rr[i][j]);
            *(bf16x8*)(dst + (size_t)j * HID) = v;
        }
    }
}

// Grouped GEMM, 128m x 64n tiles (double the active blocks of the 128x128 version:
// ~1024 blocks = 4/CU = 16 waves/CU, the latency-hiding the 2-block/CU version lacked).
//  * Expert-per-XCD: bid = ((mt*16 + nt))*8 + e -> XCD (bid%8) == e. Per-XCD working
//    set: expert's A rows (~2MB) + Wt slices; B n-slice now 128KB so re-reads are L2 hits.
//  * LDS chunk swizzle: element-chunk c of row r lives at slot c^(r&7); staging fetches
//    global chunk (p^srow) so the wave-uniform global_load_lds dest lands it right.
//  * Single-buffer LDS (24KB): dbuf was neutral at this occupancy; smaller LDS = more
//    resident blocks.
//  * Nontemporal epilogue stores keep the write-once output from evicting A/B in L2.
__launch_bounds__(256)
__global__ void moe_gemm_bf16(const __bf16* __restrict__ Xb, const __bf16* __restrict__ Wt,
                              const float* __restrict__ Bias, const float* __restrict__ scale,
                              const int* __restrict__ counts, const int* __restrict__ list,
                              float* __restrict__ out) {
    const int bid = blockIdx.x;
    const int e  = bid & 7;
    const int nt = (bid >> 3) & 15;
    const int mt = bid >> 7;

    const int cnt = counts[e];
    if (mt * 128 >= cnt) return;
    const int mvalid = min(128, cnt - mt * 128);
    const int n0 = nt * 64;

    __shared__ __bf16 As[128 * 64];
    __shared__ __bf16 Bs[64 * 64];
    __shared__ int   tok[128];
    __shared__ float scl[128];

    const int tid  = threadIdx.x;
    const int lane = tid & 63;
    const int wave = tid >> 6;

    if (tid < 128) {
        int g = mt * 128 + tid;
        int tk = (g < cnt) ? list[e * TOK + g] : 0;
        tok[tid] = tk;
        scl[tid] = (g < cnt) ? scale[tk] : 0.f;
    }
    __syncthreads();

    // Staging: A rows wave*32 + i*8 + srow (i=0..3), B rows wave*16 + i*8 + srow (i=0..1).
    const int srow = lane >> 3;
    const int gchunk = ((lane & 7) ^ srow) * 8;
    const __bf16* aptr[4];
    const __bf16* bptr[2];
#pragma unroll
    for (int i = 0; i < 4; i++) {
        int r = wave * 32 + i * 8 + srow;
        aptr[i] = Xb + (size_t)tok[r] * HID + gchunk;
    }
#pragma unroll
    for (int i = 0; i < 2; i++) {
        int r = wave * 16 + i * 8 + srow;
        bptr[i] = Wt + ((size_t)e * HID + n0 + r) * HID + gchunk;
    }

    const int ln = lane & 15;
    const int q  = lane >> 4;
    const int wm = (wave >> 1) * 64;
    const int wn = (wave & 1) * 32;
    const int rsw = ln & 7;

    floatx4 acc[4][2];
#pragma unroll
    for (int mi = 0; mi < 4; mi++)
#pragma unroll
        for (int ni = 0; ni < 2; ni++) acc[mi][ni] = (floatx4){0.f, 0.f, 0.f, 0.f};

    for (int k0 = 0; k0 < HID; k0 += 64) {
#pragma unroll
        for (int i = 0; i < 4; i++)
            __builtin_amdgcn_global_load_lds(
                (const __attribute__((address_space(1))) void*)(aptr[i] + k0),
                (__attribute__((address_space(3))) void*)(&As[(wave * 32 + i * 8) * 64]),
                16, 0, 0);
#pragma unroll
        for (int i = 0; i < 2; i++)
            __builtin_amdgcn_global_load_lds(
                (const __attribute__((address_space(1))) void*)(bptr[i] + k0),
                (__attribute__((address_space(3))) void*)(&Bs[(wave * 16 + i * 8) * 64]),
                16, 0, 0);
        __syncthreads();

#pragma unroll
        for (int kk = 0; kk < 64; kk += 32) {
            const int cb = (kk >> 3) + q;
            const int pos = (cb ^ rsw) * 8;
            bf16x8 af[4], bfv[2];
#pragma unroll
            for (int mi = 0; mi < 4; mi++)
                af[mi] = *(const bf16x8*)(&As[(wm + mi * 16 + ln) * 64 + pos]);
#pragma unroll
            for (int ni = 0; ni < 2; ni++)
                bfv[ni] = *(const bf16x8*)(&Bs[(wn + ni * 16 + ln) * 64 + pos]);
#pragma unroll
            for (int mi = 0; mi < 4; mi++)
#pragma unroll
                for (int ni = 0; ni < 2; ni++)
                    acc[mi][ni] = __builtin_amdgcn_mfma_f32_16x16x32_bf16(
                        af[mi], bfv[ni], acc[mi][ni], 0, 0, 0);
        }
        __syncthreads();
    }

    float bn[2];
#pragma unroll
    for (int ni = 0; ni < 2; ni++) bn[ni] = Bias[e * HID + n0 + wn + ni * 16 + ln];

#pragma unroll
    for (int mi = 0; mi < 4; mi++) {
#pragma unroll
        for (int r = 0; r < 4; r++) {
            int row = wm + mi * 16 + q * 4 + r;
            if (row < mvalid) {
                int t = tok[row];
                float sc = scl[row];
                size_t ob = (size_t)t * HID + n0 + wn + ln;
#pragma unroll
                for (int ni = 0; ni < 2; ni++)
                    __builtin_nontemporal_store(sc * (acc[mi][ni][r] + bn[ni]),
                                                &out[ob + ni * 16]);
            }
        }
    }
}

// ---------------- fallback (ws too small): direct fp32 reads, compile-time j ----------------
__launch_bounds__(256)
__global__ void moe_gemm_fb(const float* __restrict__ X, const float* __restrict__ W,
                            const float* __restrict__ Bias, const float* __restrict__ scale,
                            const int* __restrict__ counts, const int* __restrict__ list,
                            float* __restrict__ out) {
    const int bid = blockIdx.x;
    const int e  = bid >> 9;
    const int nt = (bid >> 6) & 7;
    const int mt = bid & 63;
    const int cnt = counts[e];
    if (mt * 128 >= cnt) return;
    const int mvalid = min(128, cnt - mt * 128);
    const int n0 = nt * 128;

    __shared__ __bf16 As[128 * 64];
    __shared__ __bf16 Bs[128 * 64];
    __shared__ int   tok[128];
    __shared__ float scl[128];

    const int tid = threadIdx.x;
    if (tid < 128) {
        int g = mt * 128 + tid;
        int tk = (g < cnt) ? list[e * TOK + g] : 0;
        tok[tid] = tk;
        scl[tid] = (g < cnt) ? scale[tk] : 0.f;
    }
    __syncthreads();

    const int c4 = tid & 15;
    const float* rp[8];
    bool rv[8];
#pragma unroll
    for (int i = 0; i < 8; i++) {
        int m = (tid >> 4) + 16 * i;
        rv[i] = (m < mvalid);
        rp[i] = X + (size_t)tok[m] * HID;
    }
    const int n4 = tid & 31;
    const int kb = tid >> 5;
    const float* wbase = W + (size_t)e * HID * HID + (size_t)(kb * 8) * HID + n0 + n4 * 4;

    const int lane = tid & 63;
    const int ln = lane & 15;
    const int q  = lane >> 4;
    const int wave = tid >> 6;
    const int wm = (wave >> 1) * 64;
    const int wn = (wave & 1) * 64;

    floatx4 acc[4][4];
#pragma unroll
    for (int mi = 0; mi < 4; mi++)
#pragma unroll
        for (int ni = 0; ni < 4; ni++) acc[mi][ni] = (floatx4){0.f, 0.f, 0.f, 0.f};

    for (int k0 = 0; k0 < HID; k0 += 64) {
#pragma unroll
        for (int i = 0; i < 8; i++) {
            int m = (tid >> 4) + 16 * i;
            float4 v = make_float4(0.f, 0.f, 0.f, 0.f);
            if (rv[i]) v = *(const float4*)(rp[i] + k0 + c4 * 4);
            bf16x4 b4;
            b4[0] = f2bf(v.x); b4[1] = f2bf(v.y); b4[2] = f2bf(v.z); b4[3] = f2bf(v.w);
            int chunk = c4 >> 1;
            int addr = m * 64 + ((chunk ^ (m & 7)) * 8) + (c4 & 1) * 4;
            *(bf16x4*)(&As[addr]) = b4;
        }
        {
            const float* wp = wbase + (size_t)k0 * HID;
            float4 rr[8];
#pragma unroll
            for (int r = 0; r < 8; r++) rr[r] = *(const float4*)(wp + (size_t)r * HID);
#pragma unroll
            for (int j = 0; j < 4; j++) {
                int n = n4 * 4 + j;
                int c = kb ^ (n & 7);
                bf16x8 pk;
                pk[0] = f2bf(j == 0 ? rr[0].x : j == 1 ? rr[0].y : j == 2 ? rr[0].z : rr[0].w);
                pk[1] = f2bf(j == 0 ? rr[1].x : j == 1 ? rr[1].y : j == 2 ? rr[1].z : rr[1].w);
                pk[2] = f2bf(j == 0 ? rr[2].x : j == 1 ? rr[2].y : j == 2 ? rr[2].z : rr[2].w);
                pk[3] = f2bf(j == 0 ? rr[3].x : j == 1 ? rr[3].y : j == 2 ? rr[3].z : rr[3].w);
                pk[4] = f2bf(j == 0 ? rr[4].x : j == 1 ? rr[4].y : j == 2 ? rr[4].z : rr[4].w);
                pk[5] = f2bf(j == 0 ? rr[5].x : j == 1 ? rr[5].y : j == 2 ? rr[5].z : rr[5].w);
                pk[6] = f2bf(j == 0 ? rr[6].x : j == 1 ? rr[6].y : j == 2 ? rr[6].z : rr[6].w);
                pk[7] = f2bf(j == 0 ? rr[7].x : j == 1 ? rr[7].y : j == 2 ? rr[7].z : rr[7].w);
                *(bf16x8*)(&Bs[n * 64 + c * 8]) = pk;
            }
        }
        __syncthreads();
#pragma unroll
        for (int kk = 0; kk < 64; kk += 32) {
            const int cbase = (kk >> 3) + q;
            bf16x8 af[4], bfv[4];
#pragma unroll
            for (int mi = 0; mi < 4; mi++) {
                int row = wm + mi * 16 + ln;
                af[mi] = *(const bf16x8*)(&As[row * 64 + ((cbase ^ (row & 7)) * 8)]);
            }
#pragma unroll
            for (int ni = 0; ni < 4; ni++) {
                int n = wn + ni * 16 + ln;
                bfv[ni] = *(const bf16x8*)(&Bs[n * 64 + ((cbase ^ (n & 7)) * 8)]);
            }
#pragma unroll
            for (int mi = 0; mi < 4; mi++)
#pragma unroll
                for (int ni = 0; ni < 4; ni++)
                    acc[mi][ni] = __builtin_amdgcn_mfma_f32_16x16x32_bf16(
                        af[mi], bfv[ni], acc[mi][ni], 0, 0, 0);
        }
        __syncthreads();
    }

    float bn[4];
#pragma unroll
    for (int ni = 0; ni < 4; ni++) bn[ni] = Bias[e * HID + n0 + wn + ni * 16 + ln];
#pragma unroll
    for (int mi = 0; mi < 4; mi++) {
#pragma unroll
        for (int r = 0; r < 4; r++) {
            int row = wm + mi * 16 + q * 4 + r;
            if (row < mvalid) {
                int t = tok[row];
                float sc = scl[row];
                size_t ob = (size_t)t * HID + n0 + wn + ln;
#pragma unroll
                for (int ni = 0; ni < 4; ni++)
                    out[ob + ni * 16] = sc * (acc[mi][ni][r] + bn[ni]);
            }
        }
    }
}

__global__ void route_fb_kernel(const float* __restrict__ gate, float* __restrict__ scale,
                                int* __restrict__ counts, int* __restrict__ list) {
    int t = blockIdx.x * blockDim.x + threadIdx.x;
    if (t >= TOK) return;
    float g[NE];
#pragma unroll
    for (int j = 0; j < NE; j++) g[j] = gate[t * NE + j];
    float gm = g[0]; int best = 0;
#pragma unroll
    for (int j = 1; j < NE; j++) {
        if (g[j] > gm) { gm = g[j]; best = j; }
    }
    float s = 0.f;
#pragma unroll
    for (int j = 0; j < NE; j++) s += __expf(g[j] - gm);
    scale[t] = 1.0f / s;
    int pos = atomicAdd(&counts[best], 1);
    list[best * TOK + pos] = t;
}

extern "C" void kernel_launch(void* const* d_in, const int* in_sizes, int n_in,
                              void* d_out, int out_size, void* d_ws, size_t ws_size,
                              hipStream_t stream) {
    const float* X    = (const float*)d_in[0];
    const float* G    = (const float*)d_in[1];
    const float* W    = (const float*)d_in[2];
    const float* Bias = (const float*)d_in[3];
    float* out = (float*)d_out;

    float* scale = (float*)d_ws;                               // 32 KB
    int* counts  = (int*)((char*)d_ws + 32768);                // 32 B (+pad)
    int* list    = (int*)((char*)d_ws + 36864);                // 256 KB -> ends 299008
    __bf16* Xb   = (__bf16*)((char*)d_ws + 299008);            // 16 MB
    __bf16* Wt   = (__bf16*)((char*)d_ws + 299008 + 16777216); // 16 MB
    const size_t need = 299008 + 2 * 16777216ULL;

    hipMemsetAsync(counts, 0, NE * sizeof(int), stream);

    if (ws_size >= need) {
        prep_kernel<<<4608, 256, 0, stream>>>(X, G, W, Xb, Wt, scale, counts, list);
        // grid: 64 mt x 16 nt x 8 e; inactive m-tiles exit immediately.
        moe_gemm_bf16<<<64 * 16 * 8, 256, 0, stream>>>(Xb, Wt, Bias, scale, counts, list, out);
    } else {
        route_fb_kernel<<<TOK / 256, 256, 0, stream>>>(G, scale, counts, list);
        moe_gemm_fb<<<NE * 64 * 8, 256, 0, stream>>>(X, W, Bias, scale, counts, list, out);
    }
}